// Round 7
// baseline (1078.375 us; speedup 1.0000x reference)
//
#include <hip/hip_runtime.h>

// AR LSTM decoder, B=256, T=2048, IN=64, H=32, NCLS=5.
//
// R10: two consumer waves ALTERNATING steps (C0: even t, C1: odd t) to beat
// the single-wave issue bound (~6.5 cy/inst, R4-R9 law). The step chain is
// only ~420 cy; issue was ~930. Each wave now has 2 step-periods to issue one
// step. h,c hand off through double-buffered LDS + per-step release/acquire
// flag (same proven protocol as the gx pipeline). Step math R9-verbatim ->
// bit-identical. Producer wave unchanged. Raw logits + postpass (R9-proven).
// Block = 192 threads: wave0=C0, wave1=producer, wave2=C1.

namespace {

typedef float f2 __attribute__((ext_vector_type(2)));
typedef unsigned int u32;
typedef const __attribute__((address_space(1))) u32* gas_ptr;
typedef __attribute__((address_space(3))) u32* las_ptr;

constexpr int Tn  = 2048;
constexpr int INn = 64;
constexpr int Hn  = 32;
constexpr int NC  = 5;
constexpr int CH  = 32;            // steps per chunk
constexpr int CHF = CH * INn;      // 2048 floats x-chunk (8 KB)
constexpr int GXF = CH * 128;      // 4096 floats gx-chunk (16 KB)
constexpr int NCHUNK = Tn / CH;    // 64

__device__ __forceinline__ float rcpf(float x) { return __builtin_amdgcn_rcpf(x); }
__device__ __forceinline__ float hadd(f2 v) { return v.x + v.y; }

__device__ __forceinline__ float rlane(float x, int l) {
    return __int_as_float(__builtin_amdgcn_readlane(__float_as_int(x), l));
}

__device__ __forceinline__ float dpp_swap1(float x) {   // quad_perm xor 1
    int t = __builtin_amdgcn_update_dpp(0, __float_as_int(x), 0xB1, 0xF, 0xF, true);
    return __int_as_float(t);
}

__device__ __forceinline__ void gl16(const float* g, float* l) {
    __builtin_amdgcn_global_load_lds((gas_ptr)g, (las_ptr)l, 16, 0, 0);
}

__device__ __forceinline__ int ld_acq(int* p) {
    return __hip_atomic_load(p, __ATOMIC_ACQUIRE, __HIP_MEMORY_SCOPE_WORKGROUP);
}
__device__ __forceinline__ void st_rel(int* p, int v) {
    __hip_atomic_store(p, v, __ATOMIC_RELEASE, __HIP_MEMORY_SCOPE_WORKGROUP);
}

__global__ __launch_bounds__(192, 1)
void ar_decode(const float* __restrict__ x,
               const float* __restrict__ W_ih,
               const float* __restrict__ W_hh,
               const float* __restrict__ b_ih,
               const float* __restrict__ b_hh,
               const float* __restrict__ W_fc,
               const float* __restrict__ b_fc,
               const float* __restrict__ emb,
               float* __restrict__ out)
{
    const int b    = blockIdx.x;
    const int tid  = threadIdx.x;
    const int wv   = tid >> 6;              // 0: C0, 1: producer, 2: C1
    const int lane = tid & 63;
    const int m    = lane >> 1;
    const int par  = lane & 1;
    const bool even = (par == 0);
    const int rA = par * Hn + m;            // i-row (par0) or f-row (par1)
    const int rB = rA + 2 * Hn;             // g-row (par0) or o-row (par1)

    __shared__ __align__(16) float s_xp[2 * CHF];   // 16 KB x staging
    __shared__ __align__(16) float s_gx[2 * GXF];   // 32 KB gx double buffer (packed f2)
    __shared__ __align__(16) float s_h[2][Hn];      // h double buffer (t&1)
    __shared__ __align__(16) float s_c[2][Hn];      // c double buffer (t&1)
    __shared__ int s_prog;    // chunks produced
    __shared__ int s_cons;    // chunks consumed
    __shared__ int s_hstep;   // last step whose h,c are published

    if (tid == 0) { s_prog = 0; s_cons = 0; s_hstep = -1; }
    __syncthreads();

    const float* __restrict__ xb = x + (size_t)b * Tn * INn;
    float* __restrict__ ob = out + (size_t)b * Tn * NC;

    if (wv == 1) {
        // ===================== producer wave (R9-verbatim) ===================
        f2 wA[INn / 2], wB[INn / 2];     // 128 VGPR — volatile-pinned loads
        {
            const volatile f2* pA = (const volatile f2*)(W_ih + (size_t)rA * 2 * INn);
            const volatile f2* pB = (const volatile f2*)(W_ih + (size_t)rB * 2 * INn);
            #pragma unroll
            for (int i = 0; i < INn / 2; ++i) { wA[i] = pA[i]; wB[i] = pB[i]; }
        }
        const float biasA = b_ih[rA] + b_hh[rA];
        const float biasB = b_ih[rB] + b_hh[rB];

        #pragma unroll
        for (int r = 0; r < 8; ++r) gl16(xb + r * 256 + lane * 4, s_xp + r * 256);
        #pragma unroll
        for (int r = 0; r < 8; ++r) gl16(xb + CHF + r * 256 + lane * 4, s_xp + CHF + r * 256);

        for (int q = 0; q < NCHUNK; ++q) {
            if (q == NCHUNK - 1) asm volatile("s_waitcnt vmcnt(0)" ::: "memory");
            else                 asm volatile("s_waitcnt vmcnt(8)" ::: "memory");
            while (ld_acq(&s_cons) < q - 1) { }   // gx buf (q&1) free?

            const f2* xc  = (const f2*)(s_xp + (q & 1) * CHF);
            f2*       gxd = (f2*)(s_gx + (q & 1) * GXF);
            #pragma unroll 2
            for (int s = 0; s < CH; ++s) {
                const f2* xt2 = xc + s * (INn / 2);
                f2 a0, a1, a2, a3, c0, c1, c2, c3;
                a0 = a1 = a2 = a3 = c0 = c1 = c2 = c3 = (f2)(0.f);
                #pragma unroll
                for (int i = 0; i < INn / 2; i += 4) {
                    const f2 x0 = xt2[i], x1 = xt2[i + 1], x2 = xt2[i + 2], x3 = xt2[i + 3];
                    a0 += wA[i] * x0;     c0 += wB[i] * x0;
                    a1 += wA[i + 1] * x1; c1 += wB[i + 1] * x1;
                    a2 += wA[i + 2] * x2; c2 += wB[i + 2] * x2;
                    a3 += wA[i + 3] * x3; c3 += wB[i + 3] * x3;
                }
                f2 g;
                g.x = biasA + hadd((a0 + a1) + (a2 + a3));
                g.y = biasB + hadd((c0 + c1) + (c2 + c3));
                gxd[s * 64 + rA] = g;                 // 1 ds_write_b64, packed
            }
            if (lane == 0) st_rel(&s_prog, q + 1);   // release: gx drained first
            if (q + 2 < NCHUNK) {                    // refill the freed x buffer
                const float* src = xb + (size_t)(q + 2) * CHF;
                float* dst = s_xp + (q & 1) * CHF;
                #pragma unroll
                for (int r = 0; r < 8; ++r) gl16(src + r * 256 + lane * 4, dst + r * 256);
            }
        }
    } else {
        // ================ consumer wave pair (alternating steps) =============
        f2 whA[Hn / 2], whB[Hn / 2];     // 64 VGPR — volatile-pinned loads
        {
            const volatile f2* pA = (const volatile f2*)(W_hh + (size_t)rA * Hn);
            const volatile f2* pB = (const volatile f2*)(W_hh + (size_t)rB * Hn);
            #pragma unroll
            for (int i = 0; i < Hn / 2; ++i) { whA[i] = pA[i]; whB[i] = pB[i]; }
        }

        // P[cls] = ( dot(W_ih[rA,64:128], emb[cls]), dot(W_ih[rB,64:128], emb[cls]) )
        f2 P[NC];
        #pragma unroll
        for (int cls = 0; cls < NC; ++cls) {
            float pa = 0.f, pb = 0.f;
            for (int i = 0; i < INn; ++i) {
                const float e = emb[cls * INn + i];
                pa += W_ih[(size_t)rA * 2 * INn + INn + i] * e;
                pb += W_ih[(size_t)rB * 2 * INn + INn + i] * e;
            }
            f2 v; v.x = pa; v.y = pb; P[cls] = v;
        }

        // per-lane classifier row: class cl = lane % 5 (lanes 0..4 store)
        const int cl = lane % 5;
        f2 wfcL[Hn / 2];                 // 32 VGPR — volatile-pinned
        {
            const volatile f2* pf = (const volatile f2*)(W_fc + (size_t)cl * Hn);
            #pragma unroll
            for (int i = 0; i < Hn / 2; ++i) wfcL[i] = pf[i];
        }
        const float bfL = b_fc[cl];

        const float zsB  = even ? 2.f : 1.f;   // g: tanh(z) = 2*sig(2z)-1
        const float mulB = even ? 2.f : 1.f;
        const float addB = even ? -1.f : 0.f;

        // activations + cell update + h,c publish (R9 math, c via argument)
        auto acts = [&](float accA, float accB, float cprev, int t) {
            const float actA = rcpf(1.f + __expf(-accA));
            const float sgB  = rcpf(1.f + __expf(-zsB * accB));
            const float actB = fmaf(sgB, mulB, addB);

            const float qA = dpp_swap1(actA);
            const float qB = dpp_swap1(actB);
            const float iv = even ? actA : qA;
            const float fv = even ? qA : actA;
            const float gv = even ? actB : qB;
            const float ov = even ? qB : actB;

            const float cn = fmaf(fv, cprev, iv * gv);
            const float e2 = __expf(2.f * cn);
            const float th = 1.f - 2.f * rcpf(e2 + 1.f);
            const float h  = ov * th;
            s_h[t & 1][m] = h;          // both parities write identical value
            s_c[t & 1][m] = cn;
        };

        const int myFirstS = (wv == 2) ? 1 : 0;   // first in-chunk step owned

        // one step t >= 1 (owned by this wave)
        auto do_step = [&](int t) {
            const int q = t >> 5, s = t & 31;
            if (s == myFirstS) {                      // chunk-entry gate
                while (ld_acq(&s_prog) < q + 1) { }
            }
            while (ld_acq(&s_hstep) < t - 1) { }      // partner gate

            const f2* hp = (const f2*)s_h[(t - 1) & 1];
            f2 hv[Hn / 2];
            #pragma unroll
            for (int i = 0; i < Hn / 2; ++i) hv[i] = hp[i];
            const float cprev = s_c[(t - 1) & 1][m];

            const float* gxc = s_gx + (q & 1) * GXF;
            const f2 g = ((const f2*)gxc)[s * 64 + rA];   // (gA, gB) packed

            // ---- classifier for step t-1 (R9-verbatim ordering) ----
            f2 z0, z1, z2, z3;
            z0 = z1 = z2 = z3 = (f2)(0.f);
            #pragma unroll
            for (int i = 0; i < Hn / 2; i += 4) {
                z0 += wfcL[i] * hv[i];         z1 += wfcL[i + 1] * hv[i + 1];
                z2 += wfcL[i + 2] * hv[i + 2]; z3 += wfcL[i + 3] * hv[i + 3];
            }
            const float z = hadd((z0 + z1) + (z2 + z3)) + bfL;
            const float p0 = rlane(z, 0), p1 = rlane(z, 1), p2 = rlane(z, 2),
                        p3 = rlane(z, 3), p4 = rlane(z, 4);

            // argmax -> Ps directly (first-max-wins, same compare sequence)
            float bv = p0; f2 Ps = P[0];
            const bool g1 = p1 > bv; bv = g1 ? p1 : bv; Ps = g1 ? P[1] : Ps;
            const bool g2 = p2 > bv; bv = g2 ? p2 : bv; Ps = g2 ? P[2] : Ps;
            const bool g3 = p3 > bv; bv = g3 ? p3 : bv; Ps = g3 ? P[3] : Ps;
            const bool g4 = p4 > bv; bv = g4 ? p4 : bv; Ps = g4 ? P[4] : Ps;

            // ---- W_hh · h(t-1) (R9-verbatim packed chains) ----
            f2 aA0, aA1, aA2, aA3, aB0, aB1, aB2, aB3;
            aA0 = aA1 = aA2 = aA3 = aB0 = aB1 = aB2 = aB3 = (f2)(0.f);
            #pragma unroll
            for (int i = 0; i < Hn / 2; i += 4) {
                const f2 h0 = hv[i], h1 = hv[i + 1], h3 = hv[i + 2], h4 = hv[i + 3];
                aA0 += whA[i] * h0;     aB0 += whB[i] * h0;
                aA1 += whA[i + 1] * h1; aB1 += whB[i + 1] * h1;
                aA2 += whA[i + 2] * h3; aB2 += whB[i + 2] * h3;
                aA3 += whA[i + 3] * h4; aB3 += whB[i + 3] * h4;
            }
            const float accA = g.x + hadd((aA0 + aA1) + (aA2 + aA3)) + Ps.x;
            const float accB = g.y + hadd((aB0 + aB1) + (aB2 + aB3)) + Ps.y;

            acts(accA, accB, cprev, t);     // publishes h(t), c(t)
            st_rel(&s_hstep, t);            // release (drains the LDS writes)

            // ---- raw logit store for t-1: lanes 0..4 store their own z ----
            if (lane < NC) ob[(size_t)(t - 1) * NC + lane] = z;

            if (s == 31) st_rel(&s_cons, q + 1);   // only C1 reaches s==31
        };

        if (wv == 0) {
            // ---- peel t=0 (h=0, c=0, prev=0 -> acc = gx + bias directly) ----
            while (ld_acq(&s_prog) < 1) { }
            const f2 g0 = ((const f2*)s_gx)[rA];
            acts(g0.x, g0.y, 0.f, 0);
            st_rel(&s_hstep, 0);
            for (int t = 2; t < Tn; t += 2) do_step(t);
        } else {
            for (int t = 1; t < Tn; t += 2) do_step(t);
            // ---- epilogue: logits for t = Tn-1 (this wave just wrote h) ----
            const f2* hp = (const f2*)s_h[(Tn - 1) & 1];
            f2 hv[Hn / 2];
            #pragma unroll
            for (int i = 0; i < Hn / 2; ++i) hv[i] = hp[i];
            f2 z0, z1, z2, z3;
            z0 = z1 = z2 = z3 = (f2)(0.f);
            #pragma unroll
            for (int i = 0; i < Hn / 2; i += 4) {
                z0 += wfcL[i] * hv[i];         z1 += wfcL[i + 1] * hv[i + 1];
                z2 += wfcL[i + 2] * hv[i + 2]; z3 += wfcL[i + 3] * hv[i + 3];
            }
            const float z = hadd((z0 + z1) + (z2 + z3)) + bfL;
            if (lane < NC) ob[(size_t)(Tn - 1) * NC + lane] = z;
        }
    }
}

// in-place log-softmax postpass: out[row][0..4] -= lse(row).
// EXACT max/sum order of the previous kernels (bit-identical results).
__global__ __launch_bounds__(256)
void logsoftmax_pp(float* __restrict__ out)
{
    const int r = blockIdx.x * 256 + threadIdx.x;    // 524288 rows
    float* p = out + (size_t)r * NC;
    const float z0 = p[0], z1 = p[1], z2 = p[2], z3 = p[3], z4 = p[4];
    float bv = z0;
    bv = (z1 > bv) ? z1 : bv;
    bv = (z2 > bv) ? z2 : bv;
    bv = (z3 > bv) ? z3 : bv;
    bv = (z4 > bv) ? z4 : bv;
    const float se = __expf(z0 - bv) + __expf(z1 - bv) + __expf(z2 - bv)
                   + __expf(z3 - bv) + __expf(z4 - bv);
    const float lse = bv + __logf(se);
    p[0] = z0 - lse;
    p[1] = z1 - lse;
    p[2] = z2 - lse;
    p[3] = z3 - lse;
    p[4] = z4 - lse;
}

} // namespace

extern "C" void kernel_launch(void* const* d_in, const int* in_sizes, int n_in,
                              void* d_out, int out_size, void* d_ws, size_t ws_size,
                              hipStream_t stream) {
    (void)in_sizes; (void)n_in; (void)d_ws; (void)ws_size; (void)out_size;
    const float* x    = (const float*)d_in[0];
    // d_in[1] x_lengths (all == T), d_in[2] edge_list: unused
    const float* W_ih = (const float*)d_in[3];
    const float* W_hh = (const float*)d_in[4];
    const float* b_ih = (const float*)d_in[5];
    const float* b_hh = (const float*)d_in[6];
    const float* W_fc = (const float*)d_in[7];
    const float* b_fc = (const float*)d_in[8];
    const float* emb  = (const float*)d_in[9];
    float* out = (float*)d_out;

    hipLaunchKernelGGL(ar_decode, dim3(256), dim3(192), 0, stream,
                       x, W_ih, W_hh, b_ih, b_hh, W_fc, b_fc, emb, out);
    hipLaunchKernelGGL(logsoftmax_pp, dim3(2048), dim3(256), 0, stream, out);
}

// Round 9
// 890.828 us; speedup vs baseline: 1.2105x; 1.2105x over previous
//
#include <hip/hip_runtime.h>

// AR LSTM decoder, B=256, T=2048, IN=64, H=32, NCLS=5.
//
// R11 (resubmit; prior run died to container-acquire infra, like R5/R9) =
// R9 base (best: 795us steady; R8/R10 proved multi-wave chains lose) +
//   (1) producer poll backoff s_sleep(4): the producer idles ~85% of each
//       chunk hammering ld_acq ds_reads, doubling CU LDS traffic and queueing
//       the consumer's critical-path reads behind it.
//   (2) spread classifier: 8-lane group per class (groups 0-4), lane j owns
//       h[4j..4j+3] (1 ds_read_b128 + 2 pk_fma, bias pre-folded into lane
//       j==0's accumulator), 3-level row_shr DPP reduce, roots (lanes
//       7,15,23,31,39) store their logit directly. ~17 insts vs ~32 for the
//       per-lane redundant dot + store-select chain.
// Step ~111 insts (from ~135). Everything else R9-verbatim.

namespace {

typedef float f2 __attribute__((ext_vector_type(2)));
typedef unsigned int u32;
typedef const __attribute__((address_space(1))) u32* gas_ptr;
typedef __attribute__((address_space(3))) u32* las_ptr;

constexpr int Tn  = 2048;
constexpr int INn = 64;
constexpr int Hn  = 32;
constexpr int NC  = 5;
constexpr int CH  = 32;            // steps per chunk
constexpr int CHF = CH * INn;      // 2048 floats x-chunk (8 KB)
constexpr int GXF = CH * 128;      // 4096 floats gx-chunk (16 KB)
constexpr int NCHUNK = Tn / CH;    // 64

__device__ __forceinline__ float rcpf(float x) { return __builtin_amdgcn_rcpf(x); }
__device__ __forceinline__ float hadd(f2 v) { return v.x + v.y; }

__device__ __forceinline__ float rlane(float x, int l) {
    return __int_as_float(__builtin_amdgcn_readlane(__float_as_int(x), l));
}

template <int CTRL, int RM, int BM, bool BC>
__device__ __forceinline__ float dpp_add(float x) {
    int t = __builtin_amdgcn_update_dpp(0, __float_as_int(x), CTRL, RM, BM, BC);
    return x + __int_as_float(t);
}

__device__ __forceinline__ float dpp_swap1(float x) {   // quad_perm xor 1
    int t = __builtin_amdgcn_update_dpp(0, __float_as_int(x), 0xB1, 0xF, 0xF, true);
    return __int_as_float(t);
}

__device__ __forceinline__ void gl16(const float* g, float* l) {
    __builtin_amdgcn_global_load_lds((gas_ptr)g, (las_ptr)l, 16, 0, 0);
}

__device__ __forceinline__ int ld_acq(int* p) {
    return __hip_atomic_load(p, __ATOMIC_ACQUIRE, __HIP_MEMORY_SCOPE_WORKGROUP);
}
__device__ __forceinline__ void st_rel(int* p, int v) {
    __hip_atomic_store(p, v, __ATOMIC_RELEASE, __HIP_MEMORY_SCOPE_WORKGROUP);
}

__global__ __launch_bounds__(128, 1)
void ar_decode(const float* __restrict__ x,
               const float* __restrict__ W_ih,
               const float* __restrict__ W_hh,
               const float* __restrict__ b_ih,
               const float* __restrict__ b_hh,
               const float* __restrict__ W_fc,
               const float* __restrict__ b_fc,
               const float* __restrict__ emb,
               float* __restrict__ out)
{
    const int b    = blockIdx.x;
    const int tid  = threadIdx.x;
    const int lane = tid & 63;
    const int m    = lane >> 1;
    const int par  = lane & 1;
    const bool even = (par == 0);
    const int rA = par * Hn + m;            // i-row (par0) or f-row (par1)
    const int rB = rA + 2 * Hn;             // g-row (par0) or o-row (par1)

    __shared__ __align__(16) float s_xp[2 * CHF];   // 16 KB x staging
    __shared__ __align__(16) float s_gx[2 * GXF];   // 32 KB gx double buffer (packed f2)
    __shared__ __align__(16) float s_h[Hn];         // h(t) broadcast
    __shared__ int s_prog;   // chunks produced
    __shared__ int s_cons;   // chunks consumed

    if (tid == 0) { s_prog = 0; s_cons = 0; }
    __syncthreads();

    const float* __restrict__ xb = x + (size_t)b * Tn * INn;
    float* __restrict__ ob = out + (size_t)b * Tn * NC;

    if (tid >= 64) {
        // ===================== producer wave (R9 + poll backoff) =============
        f2 wA[INn / 2], wB[INn / 2];     // 128 VGPR — volatile-pinned loads
        {
            const volatile f2* pA = (const volatile f2*)(W_ih + (size_t)rA * 2 * INn);
            const volatile f2* pB = (const volatile f2*)(W_ih + (size_t)rB * 2 * INn);
            #pragma unroll
            for (int i = 0; i < INn / 2; ++i) { wA[i] = pA[i]; wB[i] = pB[i]; }
        }
        const float biasA = b_ih[rA] + b_hh[rA];
        const float biasB = b_ih[rB] + b_hh[rB];

        #pragma unroll
        for (int r = 0; r < 8; ++r) gl16(xb + r * 256 + lane * 4, s_xp + r * 256);
        #pragma unroll
        for (int r = 0; r < 8; ++r) gl16(xb + CHF + r * 256 + lane * 4, s_xp + CHF + r * 256);

        for (int q = 0; q < NCHUNK; ++q) {
            if (q == NCHUNK - 1) asm volatile("s_waitcnt vmcnt(0)" ::: "memory");
            else                 asm volatile("s_waitcnt vmcnt(8)" ::: "memory");
            while (ld_acq(&s_cons) < q - 1) {        // gx buf (q&1) free?
                __builtin_amdgcn_s_sleep(4);         // back off: don't hammer LDS
            }

            const f2* xc  = (const f2*)(s_xp + (q & 1) * CHF);
            f2*       gxd = (f2*)(s_gx + (q & 1) * GXF);
            #pragma unroll 2
            for (int s = 0; s < CH; ++s) {
                const f2* xt2 = xc + s * (INn / 2);
                f2 a0, a1, a2, a3, c0, c1, c2, c3;
                a0 = a1 = a2 = a3 = c0 = c1 = c2 = c3 = (f2)(0.f);
                #pragma unroll
                for (int i = 0; i < INn / 2; i += 4) {
                    const f2 x0 = xt2[i], x1 = xt2[i + 1], x2 = xt2[i + 2], x3 = xt2[i + 3];
                    a0 += wA[i] * x0;     c0 += wB[i] * x0;
                    a1 += wA[i + 1] * x1; c1 += wB[i + 1] * x1;
                    a2 += wA[i + 2] * x2; c2 += wB[i + 2] * x2;
                    a3 += wA[i + 3] * x3; c3 += wB[i + 3] * x3;
                }
                f2 g;
                g.x = biasA + hadd((a0 + a1) + (a2 + a3));
                g.y = biasB + hadd((c0 + c1) + (c2 + c3));
                gxd[s * 64 + rA] = g;                 // 1 ds_write_b64, packed
            }
            if (lane == 0) st_rel(&s_prog, q + 1);   // release: gx drained first
            if (q + 2 < NCHUNK) {                    // refill the freed x buffer
                const float* src = xb + (size_t)(q + 2) * CHF;
                float* dst = s_xp + (q & 1) * CHF;
                #pragma unroll
                for (int r = 0; r < 8; ++r) gl16(src + r * 256 + lane * 4, dst + r * 256);
            }
        }
    } else {
        // ===================== consumer wave (serial chain) ==================
        f2 whA[Hn / 2], whB[Hn / 2];     // 64 VGPR — volatile-pinned loads
        {
            const volatile f2* pA = (const volatile f2*)(W_hh + (size_t)rA * Hn);
            const volatile f2* pB = (const volatile f2*)(W_hh + (size_t)rB * Hn);
            #pragma unroll
            for (int i = 0; i < Hn / 2; ++i) { whA[i] = pA[i]; whB[i] = pB[i]; }
        }

        // P[cls] = ( dot(W_ih[rA,64:128], emb[cls]), dot(W_ih[rB,64:128], emb[cls]) )
        f2 P[NC];
        #pragma unroll
        for (int cls = 0; cls < NC; ++cls) {
            float pa = 0.f, pb = 0.f;
            for (int i = 0; i < INn; ++i) {
                const float e = emb[cls * INn + i];
                pa += W_ih[(size_t)rA * 2 * INn + INn + i] * e;
                pb += W_ih[(size_t)rB * 2 * INn + INn + i] * e;
            }
            f2 v; v.x = pa; v.y = pb; P[cls] = v;
        }

        // ---- spread classifier setup: group g = lane>>3 owns class g (g<5);
        //      lane j = lane&7 owns h[4j..4j+3]; bias folded into j==0 lane ----
        const int j8 = lane & 7;
        const int cg = (lane >> 3) % 5;          // groups 5-7 duplicate 0-2 (unread)
        f2 wfS0, wfS1;                           // W_fc[cg][4j..4j+3] — pinned
        {
            const volatile f2* pf = (const volatile f2*)(W_fc + (size_t)cg * Hn + 4 * j8);
            wfS0 = pf[0]; wfS1 = pf[1];
        }
        f2 zini; zini.x = (j8 == 0) ? b_fc[cg] : 0.f; zini.y = 0.f;
        const bool isRoot = (j8 == 7) && (lane < 40);   // lanes 7,15,23,31,39
        float* __restrict__ obr = ob + (lane >> 3);     // root's class column

        const float zsB  = even ? 2.f : 1.f;   // g: tanh(z) = 2*sig(2z)-1
        const float mulB = even ? 2.f : 1.f;
        const float addB = even ? -1.f : 0.f;

        float cst = 0.f;

        // activations + cell update + all-lane h write (R9-verbatim math)
        auto acts = [&](float accA, float accB) {
            const float actA = rcpf(1.f + __expf(-accA));
            const float sgB  = rcpf(1.f + __expf(-zsB * accB));
            const float actB = fmaf(sgB, mulB, addB);

            const float qA = dpp_swap1(actA);
            const float qB = dpp_swap1(actB);
            const float iv = even ? actA : qA;
            const float fv = even ? qA : actA;
            const float gv = even ? actB : qB;
            const float ov = even ? qB : actB;

            cst = fmaf(fv, cst, iv * gv);
            const float e2 = __expf(2.f * cst);
            const float th = 1.f - 2.f * rcpf(e2 + 1.f);
            const float h  = ov * th;
            s_h[m] = h;                 // both parities write identical value
        };

        // spread classifier on current s_h: returns root-sum in zs (valid at
        // roots), and p0..p4 broadcast via readlane.
        auto classify = [&](float& zs, float& p0, float& p1, float& p2,
                            float& p3, float& p4) {
            const f2* hsl = (const f2*)((const char*)s_h + j8 * 16);
            const f2 hh0 = hsl[0], hh1 = hsl[1];
            f2 zp = wfS0 * hh0 + zini;           // pk_fma (bias in j==0 lane)
            zp = wfS1 * hh1 + zp;                // pk_fma
            zs = zp.x + zp.y;
            zs = dpp_add<0x111, 0xF, 0xF, true>(zs);   // row_shr:1
            zs = dpp_add<0x112, 0xF, 0xF, true>(zs);   // row_shr:2
            zs = dpp_add<0x114, 0xF, 0xF, true>(zs);   // row_shr:4 -> roots
            p0 = rlane(zs, 7);  p1 = rlane(zs, 15); p2 = rlane(zs, 23);
            p3 = rlane(zs, 31); p4 = rlane(zs, 39);
        };

        // one step t >= 1: classify h(t-1), matvec, update, raw-store t-1
        auto full_step = [&](int t, const float* gxc, int s) {
            const f2* hp = (const f2*)s_h;   // h(t-1), written by prev step
            f2 hv[Hn / 2];
            #pragma unroll
            for (int i = 0; i < Hn / 2; ++i) hv[i] = hp[i];

            const f2 g = ((const f2*)gxc)[s * 64 + rA];   // (gA, gB) packed

            // ---- spread classifier for step t-1 ----
            float zs, p0, p1, p2, p3, p4;
            classify(zs, p0, p1, p2, p3, p4);

            // argmax -> Ps directly (first-max-wins, same compare sequence)
            float bv = p0; f2 Ps = P[0];
            const bool g1 = p1 > bv; bv = g1 ? p1 : bv; Ps = g1 ? P[1] : Ps;
            const bool g2 = p2 > bv; bv = g2 ? p2 : bv; Ps = g2 ? P[2] : Ps;
            const bool g3 = p3 > bv; bv = g3 ? p3 : bv; Ps = g3 ? P[3] : Ps;
            const bool g4 = p4 > bv; bv = g4 ? p4 : bv; Ps = g4 ? P[4] : Ps;

            // ---- W_hh · h(t-1) (R9-verbatim packed chains) ----
            f2 aA0, aA1, aA2, aA3, aB0, aB1, aB2, aB3;
            aA0 = aA1 = aA2 = aA3 = aB0 = aB1 = aB2 = aB3 = (f2)(0.f);
            #pragma unroll
            for (int i = 0; i < Hn / 2; i += 4) {
                const f2 h0 = hv[i], h1 = hv[i + 1], h3 = hv[i + 2], h4 = hv[i + 3];
                aA0 += whA[i] * h0;     aB0 += whB[i] * h0;
                aA1 += whA[i + 1] * h1; aB1 += whB[i + 1] * h1;
                aA2 += whA[i + 2] * h3; aB2 += whB[i + 2] * h3;
                aA3 += whA[i + 3] * h4; aB3 += whB[i + 3] * h4;
            }
            const float accA = g.x + hadd((aA0 + aA1) + (aA2 + aA3)) + Ps.x;
            const float accB = g.y + hadd((aB0 + aB1) + (aB2 + aB3)) + Ps.y;

            acts(accA, accB);           // ends with s_h write of h(t)

            // ---- raw logit store for t-1: roots store their own class ----
            if (isRoot) obr[(size_t)(t - 1) * NC] = zs;
        };

        // ---- chunk 0: peel t=0 (h=0, prev=0 -> acc = gx + bias directly) ----
        while (ld_acq(&s_prog) < 1) { }
        {
            const float* gxc = s_gx;
            const f2 g0 = ((const f2*)gxc)[rA];
            acts(g0.x, g0.y);                       // t = 0
            #pragma unroll 4
            for (int s = 1; s < CH; ++s) full_step(s, gxc, s);
            if (lane == 0) st_rel(&s_cons, 1);
        }
        // ---- chunks 1..63 ----
        for (int q = 1; q < NCHUNK; ++q) {
            while (ld_acq(&s_prog) < q + 1) { }
            const float* gxc = s_gx + (q & 1) * GXF;
            #pragma unroll 4
            for (int s = 0; s < CH; ++s) full_step(q * CH + s, gxc, s);
            if (lane == 0) st_rel(&s_cons, q + 1);
        }
        // ---- epilogue: classifier for t = Tn-1, raw store ----
        {
            float zs, p0, p1, p2, p3, p4;
            classify(zs, p0, p1, p2, p3, p4);
            (void)p0; (void)p1; (void)p2; (void)p3; (void)p4;
            if (isRoot) obr[(size_t)(Tn - 1) * NC] = zs;
        }
    }
}

// in-place log-softmax postpass: out[row][0..4] -= lse(row).
// EXACT max/sum order of the previous kernels (bit-identical results).
__global__ __launch_bounds__(256)
void logsoftmax_pp(float* __restrict__ out)
{
    const int r = blockIdx.x * 256 + threadIdx.x;    // 524288 rows
    float* p = out + (size_t)r * NC;
    const float z0 = p[0], z1 = p[1], z2 = p[2], z3 = p[3], z4 = p[4];
    float bv = z0;
    bv = (z1 > bv) ? z1 : bv;
    bv = (z2 > bv) ? z2 : bv;
    bv = (z3 > bv) ? z3 : bv;
    bv = (z4 > bv) ? z4 : bv;
    const float se = __expf(z0 - bv) + __expf(z1 - bv) + __expf(z2 - bv)
                   + __expf(z3 - bv) + __expf(z4 - bv);
    const float lse = bv + __logf(se);
    p[0] = z0 - lse;
    p[1] = z1 - lse;
    p[2] = z2 - lse;
    p[3] = z3 - lse;
    p[4] = z4 - lse;
}

} // namespace

extern "C" void kernel_launch(void* const* d_in, const int* in_sizes, int n_in,
                              void* d_out, int out_size, void* d_ws, size_t ws_size,
                              hipStream_t stream) {
    (void)in_sizes; (void)n_in; (void)d_ws; (void)ws_size; (void)out_size;
    const float* x    = (const float*)d_in[0];
    // d_in[1] x_lengths (all == T), d_in[2] edge_list: unused
    const float* W_ih = (const float*)d_in[3];
    const float* W_hh = (const float*)d_in[4];
    const float* b_ih = (const float*)d_in[5];
    const float* b_hh = (const float*)d_in[6];
    const float* W_fc = (const float*)d_in[7];
    const float* b_fc = (const float*)d_in[8];
    const float* emb  = (const float*)d_in[9];
    float* out = (float*)d_out;

    hipLaunchKernelGGL(ar_decode, dim3(256), dim3(128), 0, stream,
                       x, W_ih, W_hh, b_ih, b_hh, W_fc, b_fc, emb, out);
    hipLaunchKernelGGL(logsoftmax_pp, dim3(2048), dim3(256), 0, stream, out);
}

// Round 10
// 747.060 us; speedup vs baseline: 1.4435x; 1.1924x over previous
//
#include <hip/hip_runtime.h>

// AR LSTM decoder, B=256, T=2048, IN=64, H=32, NCLS=5.
//
// R12 = R11 (768us steady) + chain-latency trims (R11 post-mortem: step is
// dependence-latency-bound, not issue-bound; marginal cy/inst collapsed):
//   (1) tree argmax->Ps select: 3-level strict-> tree (left/lower index wins
//       ties) == sequential first-max-wins for ALL inputs; ~16 cy shorter
//       chain. bv dropped (postpass owns log-softmax).
//   (2) gx register prefetch: step s loads step s+1's (gA,gB); per-step lgkm
//       wait covers only the hv broadcast reads.
//   (3) consumer s_setprio(1) + producer sleep(8) backoff: CU arbitration
//       favors the serial-chain wave.
// Everything else R11-verbatim (spread classifier, packed gx, raw-logit
// store + postpass).

namespace {

typedef float f2 __attribute__((ext_vector_type(2)));
typedef unsigned int u32;
typedef const __attribute__((address_space(1))) u32* gas_ptr;
typedef __attribute__((address_space(3))) u32* las_ptr;

constexpr int Tn  = 2048;
constexpr int INn = 64;
constexpr int Hn  = 32;
constexpr int NC  = 5;
constexpr int CH  = 32;            // steps per chunk
constexpr int CHF = CH * INn;      // 2048 floats x-chunk (8 KB)
constexpr int GXF = CH * 128;      // 4096 floats gx-chunk (16 KB)
constexpr int NCHUNK = Tn / CH;    // 64

__device__ __forceinline__ float rcpf(float x) { return __builtin_amdgcn_rcpf(x); }
__device__ __forceinline__ float hadd(f2 v) { return v.x + v.y; }

__device__ __forceinline__ float rlane(float x, int l) {
    return __int_as_float(__builtin_amdgcn_readlane(__float_as_int(x), l));
}

template <int CTRL, int RM, int BM, bool BC>
__device__ __forceinline__ float dpp_add(float x) {
    int t = __builtin_amdgcn_update_dpp(0, __float_as_int(x), CTRL, RM, BM, BC);
    return x + __int_as_float(t);
}

__device__ __forceinline__ float dpp_swap1(float x) {   // quad_perm xor 1
    int t = __builtin_amdgcn_update_dpp(0, __float_as_int(x), 0xB1, 0xF, 0xF, true);
    return __int_as_float(t);
}

__device__ __forceinline__ void gl16(const float* g, float* l) {
    __builtin_amdgcn_global_load_lds((gas_ptr)g, (las_ptr)l, 16, 0, 0);
}

__device__ __forceinline__ int ld_acq(int* p) {
    return __hip_atomic_load(p, __ATOMIC_ACQUIRE, __HIP_MEMORY_SCOPE_WORKGROUP);
}
__device__ __forceinline__ void st_rel(int* p, int v) {
    __hip_atomic_store(p, v, __ATOMIC_RELEASE, __HIP_MEMORY_SCOPE_WORKGROUP);
}

__global__ __launch_bounds__(128, 1)
void ar_decode(const float* __restrict__ x,
               const float* __restrict__ W_ih,
               const float* __restrict__ W_hh,
               const float* __restrict__ b_ih,
               const float* __restrict__ b_hh,
               const float* __restrict__ W_fc,
               const float* __restrict__ b_fc,
               const float* __restrict__ emb,
               float* __restrict__ out)
{
    const int b    = blockIdx.x;
    const int tid  = threadIdx.x;
    const int lane = tid & 63;
    const int m    = lane >> 1;
    const int par  = lane & 1;
    const bool even = (par == 0);
    const int rA = par * Hn + m;            // i-row (par0) or f-row (par1)
    const int rB = rA + 2 * Hn;             // g-row (par0) or o-row (par1)

    __shared__ __align__(16) float s_xp[2 * CHF];   // 16 KB x staging
    __shared__ __align__(16) float s_gx[2 * GXF];   // 32 KB gx double buffer (packed f2)
    __shared__ __align__(16) float s_h[Hn];         // h(t) broadcast
    __shared__ int s_prog;   // chunks produced
    __shared__ int s_cons;   // chunks consumed

    if (tid == 0) { s_prog = 0; s_cons = 0; }
    __syncthreads();

    const float* __restrict__ xb = x + (size_t)b * Tn * INn;
    float* __restrict__ ob = out + (size_t)b * Tn * NC;

    if (tid >= 64) {
        // ===================== producer wave (R11 + sleep 8) =================
        f2 wA[INn / 2], wB[INn / 2];     // 128 VGPR — volatile-pinned loads
        {
            const volatile f2* pA = (const volatile f2*)(W_ih + (size_t)rA * 2 * INn);
            const volatile f2* pB = (const volatile f2*)(W_ih + (size_t)rB * 2 * INn);
            #pragma unroll
            for (int i = 0; i < INn / 2; ++i) { wA[i] = pA[i]; wB[i] = pB[i]; }
        }
        const float biasA = b_ih[rA] + b_hh[rA];
        const float biasB = b_ih[rB] + b_hh[rB];

        #pragma unroll
        for (int r = 0; r < 8; ++r) gl16(xb + r * 256 + lane * 4, s_xp + r * 256);
        #pragma unroll
        for (int r = 0; r < 8; ++r) gl16(xb + CHF + r * 256 + lane * 4, s_xp + CHF + r * 256);

        for (int q = 0; q < NCHUNK; ++q) {
            if (q == NCHUNK - 1) asm volatile("s_waitcnt vmcnt(0)" ::: "memory");
            else                 asm volatile("s_waitcnt vmcnt(8)" ::: "memory");
            while (ld_acq(&s_cons) < q - 1) {        // gx buf (q&1) free?
                __builtin_amdgcn_s_sleep(8);         // back off: don't hammer LDS
            }

            const f2* xc  = (const f2*)(s_xp + (q & 1) * CHF);
            f2*       gxd = (f2*)(s_gx + (q & 1) * GXF);
            #pragma unroll 2
            for (int s = 0; s < CH; ++s) {
                const f2* xt2 = xc + s * (INn / 2);
                f2 a0, a1, a2, a3, c0, c1, c2, c3;
                a0 = a1 = a2 = a3 = c0 = c1 = c2 = c3 = (f2)(0.f);
                #pragma unroll
                for (int i = 0; i < INn / 2; i += 4) {
                    const f2 x0 = xt2[i], x1 = xt2[i + 1], x2 = xt2[i + 2], x3 = xt2[i + 3];
                    a0 += wA[i] * x0;     c0 += wB[i] * x0;
                    a1 += wA[i + 1] * x1; c1 += wB[i + 1] * x1;
                    a2 += wA[i + 2] * x2; c2 += wB[i + 2] * x2;
                    a3 += wA[i + 3] * x3; c3 += wB[i + 3] * x3;
                }
                f2 g;
                g.x = biasA + hadd((a0 + a1) + (a2 + a3));
                g.y = biasB + hadd((c0 + c1) + (c2 + c3));
                gxd[s * 64 + rA] = g;                 // 1 ds_write_b64, packed
            }
            if (lane == 0) st_rel(&s_prog, q + 1);   // release: gx drained first
            if (q + 2 < NCHUNK) {                    // refill the freed x buffer
                const float* src = xb + (size_t)(q + 2) * CHF;
                float* dst = s_xp + (q & 1) * CHF;
                #pragma unroll
                for (int r = 0; r < 8; ++r) gl16(src + r * 256 + lane * 4, dst + r * 256);
            }
        }
    } else {
        // ===================== consumer wave (serial chain) ==================
        __builtin_amdgcn_s_setprio(1);   // favor the chain wave on the CU

        f2 whA[Hn / 2], whB[Hn / 2];     // 64 VGPR — volatile-pinned loads
        {
            const volatile f2* pA = (const volatile f2*)(W_hh + (size_t)rA * Hn);
            const volatile f2* pB = (const volatile f2*)(W_hh + (size_t)rB * Hn);
            #pragma unroll
            for (int i = 0; i < Hn / 2; ++i) { whA[i] = pA[i]; whB[i] = pB[i]; }
        }

        // P[cls] = ( dot(W_ih[rA,64:128], emb[cls]), dot(W_ih[rB,64:128], emb[cls]) )
        f2 P[NC];
        #pragma unroll
        for (int cls = 0; cls < NC; ++cls) {
            float pa = 0.f, pb = 0.f;
            for (int i = 0; i < INn; ++i) {
                const float e = emb[cls * INn + i];
                pa += W_ih[(size_t)rA * 2 * INn + INn + i] * e;
                pb += W_ih[(size_t)rB * 2 * INn + INn + i] * e;
            }
            f2 v; v.x = pa; v.y = pb; P[cls] = v;
        }

        // ---- spread classifier setup: group g = lane>>3 owns class g (g<5);
        //      lane j = lane&7 owns h[4j..4j+3]; bias folded into j==0 lane ----
        const int j8 = lane & 7;
        const int cg = (lane >> 3) % 5;          // groups 5-7 duplicate 0-2 (unread)
        f2 wfS0, wfS1;                           // W_fc[cg][4j..4j+3] — pinned
        {
            const volatile f2* pf = (const volatile f2*)(W_fc + (size_t)cg * Hn + 4 * j8);
            wfS0 = pf[0]; wfS1 = pf[1];
        }
        f2 zini; zini.x = (j8 == 0) ? b_fc[cg] : 0.f; zini.y = 0.f;
        const bool isRoot = (j8 == 7) && (lane < 40);   // lanes 7,15,23,31,39
        float* __restrict__ obr = ob + (lane >> 3);     // root's class column

        const float zsB  = even ? 2.f : 1.f;   // g: tanh(z) = 2*sig(2z)-1
        const float mulB = even ? 2.f : 1.f;
        const float addB = even ? -1.f : 0.f;

        float cst = 0.f;

        // activations + cell update + all-lane h write (R9-verbatim math)
        auto acts = [&](float accA, float accB) {
            const float actA = rcpf(1.f + __expf(-accA));
            const float sgB  = rcpf(1.f + __expf(-zsB * accB));
            const float actB = fmaf(sgB, mulB, addB);

            const float qA = dpp_swap1(actA);
            const float qB = dpp_swap1(actB);
            const float iv = even ? actA : qA;
            const float fv = even ? qA : actA;
            const float gv = even ? actB : qB;
            const float ov = even ? qB : actB;

            cst = fmaf(fv, cst, iv * gv);
            const float e2 = __expf(2.f * cst);
            const float th = 1.f - 2.f * rcpf(e2 + 1.f);
            const float h  = ov * th;
            s_h[m] = h;                 // both parities write identical value
        };

        // spread classifier on current s_h: returns root-sum in zs (valid at
        // roots), and p0..p4 broadcast via readlane.
        auto classify = [&](float& zs, float& p0, float& p1, float& p2,
                            float& p3, float& p4) {
            const f2* hsl = (const f2*)((const char*)s_h + j8 * 16);
            const f2 hh0 = hsl[0], hh1 = hsl[1];
            f2 zp = wfS0 * hh0 + zini;           // pk_fma (bias in j==0 lane)
            zp = wfS1 * hh1 + zp;                // pk_fma
            zs = zp.x + zp.y;
            zs = dpp_add<0x111, 0xF, 0xF, true>(zs);   // row_shr:1
            zs = dpp_add<0x112, 0xF, 0xF, true>(zs);   // row_shr:2
            zs = dpp_add<0x114, 0xF, 0xF, true>(zs);   // row_shr:4 -> roots
            p0 = rlane(zs, 7);  p1 = rlane(zs, 15); p2 = rlane(zs, 23);
            p3 = rlane(zs, 31); p4 = rlane(zs, 39);
        };

        // one step t >= 1: classify h(t-1), matvec, update, raw-store t-1.
        // g = this step's (gA,gB), prefetched one step earlier.
        auto full_step = [&](int t, f2 g) {
            const f2* hp = (const f2*)s_h;   // h(t-1), written by prev step
            f2 hv[Hn / 2];
            #pragma unroll
            for (int i = 0; i < Hn / 2; ++i) hv[i] = hp[i];

            // ---- spread classifier for step t-1 ----
            float zs, p0, p1, p2, p3, p4;
            classify(zs, p0, p1, p2, p3, p4);

            // ---- tree argmax -> Ps (strict >, left/lower index wins ties;
            //      result == sequential first-max-wins for ALL inputs) ----
            const bool b01 = p1 > p0;
            const float v01 = b01 ? p1 : p0;   const f2 s01 = b01 ? P[1] : P[0];
            const bool b23 = p3 > p2;
            const float v23 = b23 ? p3 : p2;   const f2 s23 = b23 ? P[3] : P[2];
            const bool b03 = v23 > v01;
            const float v03 = b03 ? v23 : v01; const f2 s03 = b03 ? s23 : s01;
            const f2 Ps = (p4 > v03) ? P[4] : s03;

            // ---- W_hh · h(t-1) (R9-verbatim packed chains) ----
            f2 aA0, aA1, aA2, aA3, aB0, aB1, aB2, aB3;
            aA0 = aA1 = aA2 = aA3 = aB0 = aB1 = aB2 = aB3 = (f2)(0.f);
            #pragma unroll
            for (int i = 0; i < Hn / 2; i += 4) {
                const f2 h0 = hv[i], h1 = hv[i + 1], h3 = hv[i + 2], h4 = hv[i + 3];
                aA0 += whA[i] * h0;     aB0 += whB[i] * h0;
                aA1 += whA[i + 1] * h1; aB1 += whB[i + 1] * h1;
                aA2 += whA[i + 2] * h3; aB2 += whB[i + 2] * h3;
                aA3 += whA[i + 3] * h4; aB3 += whB[i + 3] * h4;
            }
            const float accA = g.x + hadd((aA0 + aA1) + (aA2 + aA3)) + Ps.x;
            const float accB = g.y + hadd((aB0 + aB1) + (aB2 + aB3)) + Ps.y;

            acts(accA, accB);           // ends with s_h write of h(t)

            // ---- raw logit store for t-1: roots store their own class ----
            if (isRoot) obr[(size_t)(t - 1) * NC] = zs;
        };

        // ---- chunk 0: peel t=0 (h=0, prev=0 -> acc = gx + bias directly) ----
        while (ld_acq(&s_prog) < 1) { }
        {
            const f2* gxf = (const f2*)s_gx;
            const f2 g0 = gxf[rA];
            acts(g0.x, g0.y);                       // t = 0
            f2 gcur = gxf[64 + rA];                 // s = 1
            #pragma unroll 4
            for (int s = 1; s < CH; ++s) {
                f2 gnx = gcur;
                if (s + 1 < CH) gnx = gxf[(s + 1) * 64 + rA];   // prefetch s+1
                full_step(s, gcur);
                gcur = gnx;
            }
            if (lane == 0) st_rel(&s_cons, 1);
        }
        // ---- chunks 1..63 ----
        for (int q = 1; q < NCHUNK; ++q) {
            while (ld_acq(&s_prog) < q + 1) { }
            const f2* gxf = (const f2*)(s_gx + (q & 1) * GXF);
            f2 gcur = gxf[rA];
            #pragma unroll 4
            for (int s = 0; s < CH; ++s) {
                f2 gnx = gcur;
                if (s + 1 < CH) gnx = gxf[(s + 1) * 64 + rA];   // prefetch s+1
                full_step(q * CH + s, gcur);
                gcur = gnx;
            }
            if (lane == 0) st_rel(&s_cons, q + 1);
        }
        // ---- epilogue: classifier for t = Tn-1, raw store ----
        {
            float zs, p0, p1, p2, p3, p4;
            classify(zs, p0, p1, p2, p3, p4);
            (void)p0; (void)p1; (void)p2; (void)p3; (void)p4;
            if (isRoot) obr[(size_t)(Tn - 1) * NC] = zs;
        }
    }
}

// in-place log-softmax postpass: out[row][0..4] -= lse(row).
// EXACT max/sum order of the previous kernels (bit-identical results).
__global__ __launch_bounds__(256)
void logsoftmax_pp(float* __restrict__ out)
{
    const int r = blockIdx.x * 256 + threadIdx.x;    // 524288 rows
    float* p = out + (size_t)r * NC;
    const float z0 = p[0], z1 = p[1], z2 = p[2], z3 = p[3], z4 = p[4];
    float bv = z0;
    bv = (z1 > bv) ? z1 : bv;
    bv = (z2 > bv) ? z2 : bv;
    bv = (z3 > bv) ? z3 : bv;
    bv = (z4 > bv) ? z4 : bv;
    const float se = __expf(z0 - bv) + __expf(z1 - bv) + __expf(z2 - bv)
                   + __expf(z3 - bv) + __expf(z4 - bv);
    const float lse = bv + __logf(se);
    p[0] = z0 - lse;
    p[1] = z1 - lse;
    p[2] = z2 - lse;
    p[3] = z3 - lse;
    p[4] = z4 - lse;
}

} // namespace

extern "C" void kernel_launch(void* const* d_in, const int* in_sizes, int n_in,
                              void* d_out, int out_size, void* d_ws, size_t ws_size,
                              hipStream_t stream) {
    (void)in_sizes; (void)n_in; (void)d_ws; (void)ws_size; (void)out_size;
    const float* x    = (const float*)d_in[0];
    // d_in[1] x_lengths (all == T), d_in[2] edge_list: unused
    const float* W_ih = (const float*)d_in[3];
    const float* W_hh = (const float*)d_in[4];
    const float* b_ih = (const float*)d_in[5];
    const float* b_hh = (const float*)d_in[6];
    const float* W_fc = (const float*)d_in[7];
    const float* b_fc = (const float*)d_in[8];
    const float* emb  = (const float*)d_in[9];
    float* out = (float*)d_out;

    hipLaunchKernelGGL(ar_decode, dim3(256), dim3(128), 0, stream,
                       x, W_ih, W_hh, b_ih, b_hh, W_fc, b_fc, emb, out);
    hipLaunchKernelGGL(logsoftmax_pp, dim3(2048), dim3(256), 0, stream, out);
}